// Round 2
// baseline (2024.420 us; speedup 1.0000x reference)
//
#include <hip/hip_runtime.h>

#define S 1024
#define B 8
#define NH 8
#define DH 32
#define HID 256
#define TI 16
#define TJ 8
#define NTILE (S / TJ)
#define SCALEF 0.17677669529663687f
#define CLIPV 10.0f

// LDS layout (float offsets)
#define KROWS 288            // 8 heads * 36 (pad 36 keeps float4 align + bank spread)
#define KOFF 0               // TJ*288 = 2304
#define VOFF (TJ * KROWS)    // 2304
#define BOFF (2 * TJ * KROWS)  // 4608
#define BROWS 265            // band row stride: bank = 9p + n + d -> ~2-way (free)
#define SCOFF (BOFF + 23 * BROWS + 1)   // 10704
#define SCROWS 129
#define LDS_TOT (SCOFF + TJ * SCROWS)   // 11736 floats = 46.9 KB

__global__ __launch_bounds__(256, 2)
void relattn_main_86028194939537(const float* __restrict__ q, const float* __restrict__ k,
                                 const float* __restrict__ v, const float* __restrict__ r,
                                 const float* __restrict__ bias_u, const float* __restrict__ bias_v,
                                 const int* __restrict__ mask,
                                 float* __restrict__ out, float* __restrict__ probs_raw) {
  __shared__ float sm[LDS_TOT];
  const int t = threadIdx.x;
  const int n = t & 7;
  const int il = (t >> 3) & 15;
  const int jp = t >> 7;
  const int bid = blockIdx.x;
  const int b = bid & 7;                 // b == XCD-swizzle: same-b blocks share L2
  const int i0 = (bid >> 3) * TI;
  const int i = i0 + il;

  float qu[DH], qv[DH], qvn[DH];
  {
    const float4* qr = (const float4*)(q + (i * B + b) * HID + n * DH);
    const float4* bu = (const float4*)(bias_u + n * DH);
    const float4* bv = (const float4*)(bias_v + n * DH);
#pragma unroll
    for (int dd = 0; dd < 8; ++dd) {
      float4 a = qr[dd], u4 = bu[dd], v4 = bv[dd];
      qu[4*dd+0] = a.x + u4.x; qu[4*dd+1] = a.y + u4.y;
      qu[4*dd+2] = a.z + u4.z; qu[4*dd+3] = a.w + u4.w;
      qv[4*dd+0] = a.x + v4.x; qv[4*dd+1] = a.y + v4.y;
      qv[4*dd+2] = a.z + v4.z; qv[4*dd+3] = a.w + v4.w;
    }
    if (i + 1 < S) {
      const float4* q2 = (const float4*)(q + ((i + 1) * B + b) * HID + n * DH);
#pragma unroll
      for (int dd = 0; dd < 8; ++dd) {
        float4 a = q2[dd], v4 = bv[dd];
        qvn[4*dd+0] = a.x + v4.x; qvn[4*dd+1] = a.y + v4.y;
        qvn[4*dd+2] = a.z + v4.z; qvn[4*dd+3] = a.w + v4.w;
      }
    } else {
#pragma unroll
      for (int d = 0; d < DH; ++d) qvn[d] = 0.f;
    }
  }

  float oacc[DH];
#pragma unroll
  for (int d = 0; d < DH; ++d) oacc[d] = 0.f;
  float lsum = 0.f;

  for (int jt = 0; jt < NTILE; ++jt) {
    const int j0 = jt * TJ;
    const int Pstar = i0 + TI - 1 - j0;
    const int lowBase = S - TI + j0 - i0;
    const int upBase = lowBase - S - 1;

    __syncthreads();
    // stage k, v tiles (coalesced float4, head-padded LDS layout)
    for (int u = t; u < TJ * 64; u += 256) {
      int row = u >> 6, c = u & 63;
      int gofs = ((j0 + row) * B + b) * HID + c * 4;
      int lofs = row * KROWS + (c >> 3) * 36 + (c & 7) * 4;
      *(float4*)(sm + KOFF + lofs) = *(const float4*)(k + gofs);
      *(float4*)(sm + VOFF + lofs) = *(const float4*)(v + gofs);
    }
    // stage r band: position p reads r[lowBase+p] if p<=Pstar else r[upBase+p]
    for (int u = t; u < 23 * 256; u += 256) {
      int prow = u >> 8, h = u & 255;
      int trow = (prow <= Pstar) ? (lowBase + prow) : (upBase + prow);
      float val = 0.f;
      if ((unsigned)trow < (unsigned)S) val = r[trow * HID + h];
      sm[BOFF + prow * BROWS + (h >> 5) * 33 + (h & 31)] = val;
    }
    __syncthreads();

#pragma unroll
    for (int jj = 0; jj < 4; ++jj) {
      const int jl = jp * 4 + jj;
      const int j = j0 + jl;
      // AC = qu . k_j  (k broadcast across il lanes -> cheap LDS)
      float ac = 0.f;
      const float4* krow = (const float4*)(sm + KOFF + jl * KROWS + n * 36);
#pragma unroll
      for (int dd = 0; dd < 8; ++dd) {
        float4 kv = krow[dd];
        ac = fmaf(qu[4*dd+0], kv.x, ac); ac = fmaf(qu[4*dd+1], kv.y, ac);
        ac = fmaf(qu[4*dd+2], kv.z, ac); ac = fmaf(qu[4*dd+3], kv.w, ac);
      }
      // BD via rel-shift: row p = jl+15-il of the staged band
      float bd = 0.f;
      const float* br = sm + BOFF + (jl + (TI - 1) - il) * BROWS + n * 33;
      if (j <= i) {
#pragma unroll
        for (int d = 0; d < DH; ++d) bd = fmaf(qv[d], br[d], bd);
      } else if (j > i + 1) {
#pragma unroll
        for (int d = 0; d < DH; ++d) bd = fmaf(qvn[d], br[d], bd);
      }
      float sr = (ac + bd) * SCALEF;
      sr = fminf(fmaxf(sr, -15.f), 15.f);
      float e2 = __expf(2.f * sr);
      float scv = CLIPV * (e2 - 1.f) / (e2 + 1.f);   // 10*tanh
      sm[SCOFF + jl * SCROWS + il * 8 + n] = scv;
      // per-head softmax accumulation (scores bounded +-10: no max-sub needed)
      float pw = __expf(scv);
      lsum += pw;
      const float4* vrow = (const float4*)(sm + VOFF + jl * KROWS + n * 36);
#pragma unroll
      for (int dd = 0; dd < 8; ++dd) {
        float4 vv = vrow[dd];
        oacc[4*dd+0] = fmaf(pw, vv.x, oacc[4*dd+0]);
        oacc[4*dd+1] = fmaf(pw, vv.y, oacc[4*dd+1]);
        oacc[4*dd+2] = fmaf(pw, vv.z, oacc[4*dd+2]);
        oacc[4*dd+3] = fmaf(pw, vv.w, oacc[4*dd+3]);
      }
    }
    __syncthreads();
    // head-mean logits -> masked raw logits to probs buffer (normalized in k2)
    if (t < TI * TJ) {
      int li = t >> 3, lj = t & 7;
      float ssum = 0.f;
#pragma unroll
      for (int nn = 0; nn < 8; ++nn) ssum += sm[SCOFF + lj * SCROWS + li * 8 + nn];
      float logit = ssum * 0.125f;
      int gi = i0 + li, gj = j0 + lj;
      int gofs = (gi * S + gj) * B + b;
      probs_raw[gofs] = (mask[gofs] != 0) ? -1e30f : logit;
    }
  }

  // combine the two j-phase partials (jp=0/1) via LDS, write out
  __syncthreads();
  if (jp == 1) {
    float* red = sm + (t - 128) * 33;
#pragma unroll
    for (int d = 0; d < DH; ++d) red[d] = oacc[d];
    red[DH] = lsum;
  }
  __syncthreads();
  if (jp == 0) {
    const float* red = sm + t * 33;
#pragma unroll
    for (int d = 0; d < DH; ++d) oacc[d] += red[d];
    lsum += red[DH];
    float inv = 1.f / lsum;
    float4* orow = (float4*)(out + (i * B + b) * HID + n * DH);
#pragma unroll
    for (int dd = 0; dd < 8; ++dd) {
      float4 o4;
      o4.x = oacc[4*dd+0] * inv; o4.y = oacc[4*dd+1] * inv;
      o4.z = oacc[4*dd+2] * inv; o4.w = oacc[4*dd+3] * inv;
      orow[dd] = o4;
    }
  }
}

__global__ __launch_bounds__(256)
void relattn_probs_norm_86028194939537(float* __restrict__ probs) {
  const int t = threadIdx.x;
  const int bid = blockIdx.x;
  const int b = bid & 7;
  const int i = bid >> 3;
  float vals[4];
  float s = 0.f;
#pragma unroll
  for (int kk = 0; kk < 4; ++kk) {
    int j = t + 256 * kk;
    vals[kk] = probs[(i * S + j) * B + b];
    s += __expf(vals[kk]);          // masked rows are -1e30 -> exp flushes to 0
  }
#pragma unroll
  for (int off = 32; off > 0; off >>= 1) s += __shfl_down(s, off, 64);
  __shared__ float ws[4];
  __shared__ float tot;
  if ((t & 63) == 0) ws[t >> 6] = s;
  __syncthreads();
  if (t == 0) tot = ws[0] + ws[1] + ws[2] + ws[3];
  __syncthreads();
  float inv = 1.f / tot;
#pragma unroll
  for (int kk = 0; kk < 4; ++kk) {
    int j = t + 256 * kk;
    probs[(i * S + j) * B + b] = __expf(vals[kk]) * inv;
  }
}

extern "C" void kernel_launch(void* const* d_in, const int* in_sizes, int n_in,
                              void* d_out, int out_size, void* d_ws, size_t ws_size,
                              hipStream_t stream) {
  const float* q  = (const float*)d_in[0];
  const float* k  = (const float*)d_in[1];
  const float* v  = (const float*)d_in[2];
  const float* r  = (const float*)d_in[3];
  const float* bu = (const float*)d_in[4];
  const float* bv = (const float*)d_in[5];
  const int* mask = (const int*)d_in[6];
  float* out = (float*)d_out;
  float* probs = out + S * B * HID;   // output 1 region, also holds raw logits between k1/k2

  relattn_main_86028194939537<<<dim3((S / TI) * B), dim3(256), 0, stream>>>(
      q, k, v, r, bu, bv, mask, out, probs);
  relattn_probs_norm_86028194939537<<<dim3(S * B), dim3(256), 0, stream>>>(probs);
}